// Round 1
// baseline (64.163 us; speedup 1.0000x reference)
//
#include <hip/hip_runtime.h>
#include <math.h>

#define BB 32
#define NN 4096
#define DD 512

__device__ __forceinline__ float wave_reduce_add(float v) {
    // 64-lane butterfly: every lane ends with the full sum
    v += __shfl_xor(v, 32, 64);
    v += __shfl_xor(v, 16, 64);
    v += __shfl_xor(v, 8, 64);
    v += __shfl_xor(v, 4, 64);
    v += __shfl_xor(v, 2, 64);
    v += __shfl_xor(v, 1, 64);
    return v;
}

// One block (64 threads) per batch: compute ||q||, zero counter and attn-sum.
__global__ __launch_bounds__(64) void sim_init_kernel(
    const float* __restrict__ q, float* __restrict__ qnorm,
    int* __restrict__ count, float* __restrict__ asum)
{
    int b = blockIdx.x;
    int lane = threadIdx.x;
    const float4* qr = reinterpret_cast<const float4*>(q + (size_t)b * DD);
    float4 a = qr[lane * 2];
    float4 c = qr[lane * 2 + 1];
    float s = a.x * a.x + a.y * a.y + a.z * a.z + a.w * a.w
            + c.x * c.x + c.y * c.y + c.z * c.z + c.w * c.w;
    s = wave_reduce_add(s);
    if (lane == 0) {
        qnorm[b] = sqrtf(s);
        count[b] = 0;
        asum[b]  = 0.0f;
    }
}

// One wave per key row: cosine sim; append passing rows to a compact list.
__global__ __launch_bounds__(256) void sim_pass1_kernel(
    const float* __restrict__ q, const float* __restrict__ key,
    const unsigned char* __restrict__ mask, const float* __restrict__ qnorm,
    int* __restrict__ count, float* __restrict__ asum, int2* __restrict__ list)
{
    const int lane = threadIdx.x & 63;
    const int wave = threadIdx.x >> 6;
    const int wpb  = blockDim.x >> 6;
    const long long total = (long long)BB * NN;
    const long long stride = (long long)gridDim.x * wpb;

    for (long long r = (long long)blockIdx.x * wpb + wave; r < total; r += stride) {
        const int b = (int)(r >> 12);        // N = 4096
        const int n = (int)(r & (NN - 1));
        const float4* kr = reinterpret_cast<const float4*>(key + (size_t)r * DD);
        const float4* qr = reinterpret_cast<const float4*>(q + (size_t)b * DD);
        float4 k0 = kr[lane * 2];
        float4 k1 = kr[lane * 2 + 1];
        float4 q0 = qr[lane * 2];
        float4 q1 = qr[lane * 2 + 1];

        float dot = k0.x * q0.x + k0.y * q0.y + k0.z * q0.z + k0.w * q0.w
                  + k1.x * q1.x + k1.y * q1.y + k1.z * q1.z + k1.w * q1.w;
        float k2  = k0.x * k0.x + k0.y * k0.y + k0.z * k0.z + k0.w * k0.w
                  + k1.x * k1.x + k1.y * k1.y + k1.z * k1.z + k1.w * k1.w;

        dot = wave_reduce_add(dot);
        k2  = wave_reduce_add(k2);

        if (lane == 0) {
            float denom = fmaxf(qnorm[b] * sqrtf(k2), 1e-8f);
            float attn  = dot / denom;
            if (attn >= 0.9f && mask[r] == 0) {
                int idx = atomicAdd(&count[b], 1);
                list[(size_t)b * NN + idx] = make_int2(n, __float_as_int(attn));
                atomicAdd(&asum[b], attn);
            }
        }
    }
}

// One block per batch, one thread per output element: gather selected value rows.
__global__ __launch_bounds__(512) void sim_pass2_kernel(
    const float* __restrict__ value, const int* __restrict__ count,
    const float* __restrict__ asum, const int2* __restrict__ list,
    float* __restrict__ out)
{
    const int b = blockIdx.x;
    const int d = threadIdx.x;
    const int c = count[b];
    const float inv = 1.0f / (asum[b] + 1e-8f);
    float acc = 0.0f;
    for (int i = 0; i < c; ++i) {
        int2 e = list[(size_t)b * NN + i];
        float a = __int_as_float(e.y);
        acc += a * value[((size_t)b * NN + e.x) * DD + d];
    }
    out[(size_t)b * DD + d] = acc * inv;
}

extern "C" void kernel_launch(void* const* d_in, const int* in_sizes, int n_in,
                              void* d_out, int out_size, void* d_ws, size_t ws_size,
                              hipStream_t stream) {
    const float* query = (const float*)d_in[0];               // [B, D]
    const float* key   = (const float*)d_in[1];               // [B, N, D]
    const float* value = (const float*)d_in[2];               // [B, N, D]
    const unsigned char* mask = (const unsigned char*)d_in[3];// [B, N] bool
    float* out = (float*)d_out;                               // [B, D]

    char* ws = (char*)d_ws;
    float* qnorm = (float*)(ws);          // 32 floats
    int*   count = (int*)(ws + 256);      // 32 ints
    float* asum  = (float*)(ws + 512);    // 32 floats
    int2*  list  = (int2*)(ws + 1024);    // B*N entries worst case = 1 MiB

    sim_init_kernel<<<BB, 64, 0, stream>>>(query, qnorm, count, asum);
    sim_pass1_kernel<<<2048, 256, 0, stream>>>(query, key, mask, qnorm,
                                               count, asum, list);
    sim_pass2_kernel<<<BB, DD, 0, stream>>>(value, count, asum, list, out);
}

// Round 3
// 54.676 us; speedup vs baseline: 1.1735x; 1.1735x over previous
//
#include <hip/hip_runtime.h>
#include <math.h>

#define BB 32
#define NN 4096
#define DD 512
#define ROWS_PER_WAVE 16   // 8192 waves * 16 rows = 131072 = B*N

typedef float v4f __attribute__((ext_vector_type(4)));

// 5-stage butterfly over a 32-lane half-wave; all 32 lanes end with the sum.
__device__ __forceinline__ float half_reduce_add(float v) {
    v += __shfl_xor(v, 16, 64);
    v += __shfl_xor(v, 8, 64);
    v += __shfl_xor(v, 4, 64);
    v += __shfl_xor(v, 2, 64);
    v += __shfl_xor(v, 1, 64);
    return v;
}

__device__ __forceinline__ float dot4(v4f a, v4f b) {
    return a.x * b.x + a.y * b.y + a.z * b.z + a.w * b.w;
}

// Each wave owns 16 consecutive rows of one batch; two rows processed per
// iteration (half-wave per row, 64 B/lane, per-instruction contiguous loads).
__global__ __launch_bounds__(256) void sim_pass1_kernel(
    const float* __restrict__ q, const float* __restrict__ key,
    const unsigned char* __restrict__ mask,
    int* __restrict__ count, int2* __restrict__ list)
{
    const int lane = threadIdx.x & 63;
    const int half = lane >> 5;
    const int l32  = lane & 31;
    const int wave = threadIdx.x >> 6;
    const int wg   = blockIdx.x * (blockDim.x >> 6) + wave;   // 0..8191
    const int r0   = wg * ROWS_PER_WAVE;                      // chunk stays in one batch
    const int b    = r0 >> 12;                                // N = 4096

    // Load q once per wave (16 floats/lane32, per-instruction contiguous).
    const v4f* qr = reinterpret_cast<const v4f*>(q + (size_t)b * DD);
    v4f qv0 = qr[l32 + 0];
    v4f qv1 = qr[l32 + 32];
    v4f qv2 = qr[l32 + 64];
    v4f qv3 = qr[l32 + 96];
    float qq = dot4(qv0, qv0) + dot4(qv1, qv1) + dot4(qv2, qv2) + dot4(qv3, qv3);
    qq = half_reduce_add(qq);
    const float qn = sqrtf(qq);

#pragma unroll 2
    for (int i = 0; i < ROWS_PER_WAVE / 2; ++i) {
        const int row = r0 + 2 * i + half;
        const v4f* kr = reinterpret_cast<const v4f*>(key + (size_t)row * DD);
        v4f k0 = __builtin_nontemporal_load(&kr[l32 + 0]);
        v4f k1 = __builtin_nontemporal_load(&kr[l32 + 32]);
        v4f k2 = __builtin_nontemporal_load(&kr[l32 + 64]);
        v4f k3 = __builtin_nontemporal_load(&kr[l32 + 96]);

        float dot = dot4(k0, qv0) + dot4(k1, qv1) + dot4(k2, qv2) + dot4(k3, qv3);
        float kk  = dot4(k0, k0) + dot4(k1, k1) + dot4(k2, k2) + dot4(k3, k3);

        dot = half_reduce_add(dot);
        kk  = half_reduce_add(kk);

        if (l32 == 0) {
            float denom = fmaxf(qn * sqrtf(kk), 1e-8f);
            float attn  = dot / denom;
            if (attn >= 0.9f && mask[row] == 0) {
                int idx = atomicAdd(&count[b], 1);
                list[(size_t)b * NN + idx] = make_int2(row & (NN - 1), __float_as_int(attn));
            }
        }
    }
}

// One block per batch, one thread per output element: gather selected rows.
// asum recomputed here from the list (removes the float atomic in pass1).
__global__ __launch_bounds__(512) void sim_pass2_kernel(
    const float* __restrict__ value, const int* __restrict__ count,
    const int2* __restrict__ list, float* __restrict__ out)
{
    const int b = blockIdx.x;
    const int d = threadIdx.x;
    const int c = count[b];
    float asum = 0.0f;
    float acc  = 0.0f;
    for (int i = 0; i < c; ++i) {
        int2 e = list[(size_t)b * NN + i];
        float a = __int_as_float(e.y);
        asum += a;
        acc  += a * value[((size_t)b * NN + e.x) * DD + d];
    }
    out[(size_t)b * DD + d] = acc / (asum + 1e-8f);
}

extern "C" void kernel_launch(void* const* d_in, const int* in_sizes, int n_in,
                              void* d_out, int out_size, void* d_ws, size_t ws_size,
                              hipStream_t stream) {
    const float* query = (const float*)d_in[0];                // [B, D]
    const float* key   = (const float*)d_in[1];                // [B, N, D]
    const float* value = (const float*)d_in[2];                // [B, N, D]
    const unsigned char* mask = (const unsigned char*)d_in[3]; // [B, N] bool
    float* out = (float*)d_out;                                // [B, D]

    char* ws = (char*)d_ws;
    int*  count = (int*)(ws);            // 32 ints
    int2* list  = (int2*)(ws + 256);     // B*N worst case = 1 MiB

    (void)hipMemsetAsync(count, 0, BB * sizeof(int), stream);
    sim_pass1_kernel<<<2048, 256, 0, stream>>>(query, key, mask, count, list);
    sim_pass2_kernel<<<BB, DD, 0, stream>>>(value, count, list, out);
}